// Round 1
// baseline (220.879 us; speedup 1.0000x reference)
//
#include <hip/hip_runtime.h>

using u64 = unsigned long long;
using u32 = unsigned int;
using u16 = unsigned short;

typedef short bf16x8 __attribute__((ext_vector_type(8)));
typedef float f32x4  __attribute__((ext_vector_type(4)));

#define NB   6000
#define CB94 94          // ceil(6000/64)
#define THRF 0.7f

__device__ __forceinline__ u16 f2bf(float f) {
    u32 u = __float_as_uint(f);
    return (u16)((u + 0x7FFFu + ((u >> 16) & 1u)) >> 16);
}

__device__ __forceinline__ void gload_lds16(const void* g, void* l) {
    __builtin_amdgcn_global_load_lds((const __attribute__((address_space(1))) void*)g,
                                     (__attribute__((address_space(3))) void*)l, 16, 0, 0);
}

// ---------------- NMS ----------------

__global__ void rank_kernel(const float* __restrict__ scores, int* __restrict__ rank) {
    __shared__ float sj[256];
    int t = threadIdx.x;
    int j0 = blockIdx.y * 256;
    int jj = j0 + t;
    sj[t] = (jj < NB) ? scores[jj] : 0.f;
    __syncthreads();
    int i = blockIdx.x * 256 + t;
    if (i >= NB) return;
    float si = scores[i];
    int jn = min(256, NB - j0);
    int cnt = 0;
    for (int k = 0; k < jn; ++k) {
        float s = sj[k];
        int j = j0 + k;
        cnt += (s > si) || (s == si && j < i);
    }
    if (cnt) atomicAdd(&rank[i], cnt);
}

__global__ void scatter_kernel(const float* __restrict__ boxes, const int* __restrict__ rank,
                               int* __restrict__ order, float4* __restrict__ sboxes) {
    int i = blockIdx.x * 256 + threadIdx.x;
    if (i >= NB) return;
    int r = rank[i];
    order[r] = i;
    sboxes[r] = ((const float4*)boxes)[i];
}

__global__ __launch_bounds__(64) void mask_kernel(const float4* __restrict__ sboxes,
                                                  u64* __restrict__ mask,
                                                  u64* __restrict__ bitmap) {
    int cb = blockIdx.x, rb = blockIdx.y;
    if (cb < rb) return;
    __shared__ float4 cbox[64];
    __shared__ float  carea[64];
    int t = threadIdx.x;
    int j = cb * 64 + t;
    if (j < NB) {
        float4 b = sboxes[j];
        cbox[t] = b;
        carea[t] = (b.z - b.x) * (b.w - b.y);
    }
    __syncthreads();
    int i = rb * 64 + t;
    if (i >= NB) return;
    float4 a = sboxes[i];
    float aarea = (a.z - a.x) * (a.w - a.y);
    int jn = min(64, NB - cb * 64);
    u64 bits = 0;
    for (int k = 0; k < jn; ++k) {
        int jg = cb * 64 + k;
        if (jg <= i) continue;
        float4 b = cbox[k];
        float iw = fmaxf(fminf(a.z, b.z) - fmaxf(a.x, b.x), 0.f);
        float ih = fmaxf(fminf(a.w, b.w) - fmaxf(a.y, b.y), 0.f);
        float inter = __fmul_rn(iw, ih);
        float denom = __fsub_rn(__fadd_rn(aarea, carea[k]), inter);
        float iou = __fdiv_rn(inter, denom);
        if (iou >= THRF) bits |= 1ull << k;
    }
    mask[(size_t)i * CB94 + cb] = bits;
    if (bits) atomicOr(&bitmap[i * 2 + (cb >> 6)], 1ull << (cb & 63));
}

__global__ __launch_bounds__(256) void scan_kernel(const u64* __restrict__ gmask,
                                                   const u64* __restrict__ gbitmap,
                                                   const int* __restrict__ order,
                                                   float* __restrict__ keepF,
                                                   float* __restrict__ out) {
    __shared__ u64 diagLDS[CB94 * 64];   // 48128 B
    __shared__ u64 bmLDS[NB * 2];        // 96000 B
    __shared__ u64 removedLDS[CB94];
    int t = threadIdx.x;
    for (int idx = t; idx < CB94 * 64; idx += 256) {
        int w = idx >> 6, b = idx & 63;
        int r = w * 64 + b;
        diagLDS[idx] = (r < NB) ? gmask[(size_t)r * CB94 + w] : 0ull;
    }
    for (int idx = t; idx < NB * 2; idx += 256) bmLDS[idx] = gbitmap[idx];
    for (int idx = t; idx < CB94; idx += 256) removedLDS[idx] = 0ull;
    __syncthreads();

    if (t < 64) {
        int l = t;
        for (int w = 0; w < CB94; ++w) {
            u64 rm = removedLDS[w];
            u64 dg = diagLDS[w * 64 + l];
            u64 valid = (w == CB94 - 1) ? ((1ull << 48) - 1ull) : ~0ull;
            u64 nz = __ballot(dg != 0ull);
            u64 cand = nz & ~rm & valid;
            while (cand) {
                int b = __ffsll(cand) - 1;
                u64 db = __shfl(dg, b, 64);
                rm |= db;
                cand &= ~rm;
                cand &= ~(1ull << b);
            }
            if (l == 0) removedLDS[w] = rm;
            u64 kept = valid & ~rm;
            if ((kept >> l) & 1ull) {
                int r = w * 64 + l;
                u64 bm0 = bmLDS[2 * r], bm1 = bmLDS[2 * r + 1];
                if (w < 63) bm0 &= ~((2ull << w) - 1ull); else bm0 = 0ull;
                if (w >= 64) bm1 &= ~((2ull << (w - 64)) - 1ull);
                while (bm0) {
                    int tt = __ffsll(bm0) - 1;
                    bm0 &= bm0 - 1;
                    u64 mw = gmask[(size_t)r * CB94 + tt];
                    atomicOr(&removedLDS[tt], mw);
                }
                while (bm1) {
                    int b2 = __ffsll(bm1) - 1;
                    bm1 &= bm1 - 1;
                    int tt = 64 + b2;
                    u64 mw = gmask[(size_t)r * CB94 + tt];
                    atomicOr(&removedLDS[tt], mw);
                }
            }
        }
    }
    __syncthreads();
    for (int k = t; k < NB; k += 256) {
        int sup = (int)((removedLDS[k >> 6] >> (k & 63)) & 1ull);
        float kf = sup ? 0.f : 1.f;
        int orig = order[k];
        keepF[orig] = kf;
        out[150000 + orig] = kf;   // keep section of d_out
    }
}

// ---------------- MLP path ----------------

// maxpool 14x14x64 -> 2x2x64, write bf16 flat [6000][256]
__global__ __launch_bounds__(256) void pool_kernel(const float* __restrict__ roi,
                                                   u16* __restrict__ flat) {
    int t = threadIdx.x;
    int n = blockIdx.x * 4 + (t >> 6);
    int lane = t & 63;
    int p = lane >> 4, li = lane & 15;
    int ph = p >> 1, pw = p & 1;
    const float4* base = (const float4*)roi;
    float mx0 = -3.4e38f, mx1 = -3.4e38f, mx2 = -3.4e38f, mx3 = -3.4e38f;
#pragma unroll
    for (int i = 0; i < 7; ++i)
#pragma unroll
        for (int j = 0; j < 7; ++j) {
            float4 v = base[((n * 14 + ph * 7 + i) * 14 + pw * 7 + j) * 16 + li];
            mx0 = fmaxf(mx0, v.x); mx1 = fmaxf(mx1, v.y);
            mx2 = fmaxf(mx2, v.z); mx3 = fmaxf(mx3, v.w);
        }
    int ob = n * 256 + p * 64 + li * 4;
    u64 pack = (u64)f2bf(mx0) | ((u64)f2bf(mx1) << 16) | ((u64)f2bf(mx2) << 32) | ((u64)f2bf(mx3) << 48);
    *(u64*)&flat[ob] = pack;
}

__global__ void prep_w1t(const float* __restrict__ W1, u16* __restrict__ w1t) {
    int idx = blockIdx.x * 256 + threadIdx.x;
    if (idx >= 1024 * 256) return;
    int n = idx >> 8, k = idx & 255;
    w1t[idx] = f2bf(W1[k * 1024 + n]);
}

__global__ void prep_w2t(const float* __restrict__ Wc, const float* __restrict__ Wr,
                         u16* __restrict__ w2t) {
    int idx = blockIdx.x * 256 + threadIdx.x;
    if (idx >= 32 * 1024) return;
    int o = idx >> 10, k = idx & 1023;
    float v = 0.f;
    if (o < 21) v = Wc[k * 21 + o];
    else if (o < 25) v = Wr[k * 4 + (o - 21)];
    w2t[idx] = f2bf(v);
}

// h = relu(flat @ W1 + b1), bf16 out [6000][1024]; 128x128 tile, 4 waves
__global__ __launch_bounds__(256) void gemm1_kernel(const u16* __restrict__ flat,
                                                    const u16* __restrict__ w1t,
                                                    const float* __restrict__ b1,
                                                    u16* __restrict__ h) {
    __shared__ __align__(16) u16 Alds[128 * 32];
    __shared__ __align__(16) u16 Blds[128 * 32];
    int t = threadIdx.x;
    int c0 = blockIdx.x * 128;
    int r0 = blockIdx.y * 128;
    int lane = t & 63, wid = t >> 6, wr = wid >> 1, wc = wid & 1;
    int lrow = lane & 15, kblk = lane >> 4;
    f32x4 acc[4][4] = {};
    for (int step = 0; step < 8; ++step) {
        int k0 = step * 32;
#pragma unroll
        for (int it = 0; it < 2; ++it) {
            int chunk = it * 256 + t;
            int row = chunk >> 2, kc = chunk & 3;
            int ar = r0 + row; ar = ar < (NB - 1) ? ar : (NB - 1);
            gload_lds16(flat + ar * 256 + k0 + kc * 8, &Alds[chunk * 8]);
            gload_lds16(w1t + (c0 + row) * 256 + k0 + kc * 8, &Blds[chunk * 8]);
        }
        __syncthreads();
        bf16x8 a[4], b[4];
#pragma unroll
        for (int m = 0; m < 4; ++m) a[m] = *(const bf16x8*)&Alds[(wr * 64 + m * 16 + lrow) * 32 + kblk * 8];
#pragma unroll
        for (int n = 0; n < 4; ++n) b[n] = *(const bf16x8*)&Blds[(wc * 64 + n * 16 + lrow) * 32 + kblk * 8];
#pragma unroll
        for (int m = 0; m < 4; ++m)
#pragma unroll
            for (int n = 0; n < 4; ++n)
                acc[m][n] = __builtin_amdgcn_mfma_f32_16x16x32_bf16(a[m], b[n], acc[m][n], 0, 0, 0);
        __syncthreads();
    }
    int rj = lane >> 4;
#pragma unroll
    for (int n = 0; n < 4; ++n) {
        int col = c0 + wc * 64 + n * 16 + lrow;
        float bias = b1[col];
#pragma unroll
        for (int m = 0; m < 4; ++m) {
            int rbase = r0 + wr * 64 + m * 16 + rj * 4;
#pragma unroll
            for (int j = 0; j < 4; ++j) {
                int r = rbase + j;
                if (r < NB) {
                    float v = acc[m][n][j] + bias;
                    v = v > 0.f ? v : 0.f;
                    h[r * 1024 + col] = f2bf(v);
                }
            }
        }
    }
}

// scores[6000][32] = h @ [Wc|Wr] (bf16 MFMA), 64 rows/block, K-rounds of 128
__global__ __launch_bounds__(256) void gemm2_kernel(const u16* __restrict__ h,
                                                    const u16* __restrict__ w2t,
                                                    float* __restrict__ scores) {
    __shared__ __align__(16) u16 Alds[4 * 64 * 32];  // 16 KB
    __shared__ __align__(16) u16 Blds[4 * 32 * 32];  // 8 KB
    int t = threadIdx.x, lane = t & 63, w = t >> 6;
    int r0 = blockIdx.x * 64;
    int lrow = lane & 15, kblk = lane >> 4;
    f32x4 acc[2] = {};
    for (int round = 0; round < 8; ++round) {
        int kr0 = round * 128;
#pragma unroll
        for (int it = 0; it < 4; ++it) {
            int chunk = it * 256 + t;
            int kk = chunk >> 8, rem = chunk & 255, row = rem >> 2, kc = rem & 3;
            int ar = r0 + row; ar = ar < (NB - 1) ? ar : (NB - 1);
            gload_lds16(h + ar * 1024 + kr0 + kk * 32 + kc * 8, &Alds[chunk * 8]);
        }
#pragma unroll
        for (int it = 0; it < 2; ++it) {
            int chunk = it * 256 + t;
            int kk = chunk >> 7, rem = chunk & 127, orow = rem >> 2, kc = rem & 3;
            gload_lds16(w2t + orow * 1024 + kr0 + kk * 32 + kc * 8, &Blds[chunk * 8]);
        }
        __syncthreads();
#pragma unroll
        for (int kk = 0; kk < 4; ++kk) {
            bf16x8 a = *(const bf16x8*)&Alds[kk * 2048 + (w * 16 + lrow) * 32 + kblk * 8];
#pragma unroll
            for (int nf = 0; nf < 2; ++nf) {
                bf16x8 b = *(const bf16x8*)&Blds[kk * 1024 + (nf * 16 + lrow) * 32 + kblk * 8];
                acc[nf] = __builtin_amdgcn_mfma_f32_16x16x32_bf16(a, b, acc[nf], 0, 0, 0);
            }
        }
        __syncthreads();
    }
#pragma unroll
    for (int nf = 0; nf < 2; ++nf) {
        int col = nf * 16 + lrow;
#pragma unroll
        for (int j = 0; j < 4; ++j) {
            int r = r0 + w * 16 + (lane >> 4) * 4 + j;
            if (r < NB) scores[r * 32 + col] = acc[nf][j];
        }
    }
}

__global__ void epilogue_kernel(const float* __restrict__ scores, const float* __restrict__ keepF,
                                const float* __restrict__ bc, const float* __restrict__ br,
                                float* __restrict__ out) {
    int r = blockIdx.x * 256 + threadIdx.x;
    if (r >= NB) return;
    float kf = keepF[r];
    float lg[21];
    float m = -3.4e38f;
#pragma unroll
    for (int o = 0; o < 21; ++o) {
        lg[o] = scores[r * 32 + o] + bc[o];
        m = fmaxf(m, lg[o]);
    }
    float s = 0.f;
#pragma unroll
    for (int o = 0; o < 21; ++o) {
        lg[o] = expf(lg[o] - m);
        s += lg[o];
    }
    float inv = kf / s;
#pragma unroll
    for (int o = 0; o < 21; ++o) out[r * 21 + o] = lg[o] * inv;
#pragma unroll
    for (int o = 0; o < 4; ++o) out[126000 + r * 4 + o] = (scores[r * 32 + 21 + o] + br[o]) * kf;
}

// ---------------- launch ----------------

extern "C" void kernel_launch(void* const* d_in, const int* in_sizes, int n_in,
                              void* d_out, int out_size, void* d_ws, size_t ws_size,
                              hipStream_t stream) {
    (void)in_sizes; (void)n_in; (void)out_size; (void)ws_size;
    const float* boxes  = (const float*)d_in[0];
    const float* scores = (const float*)d_in[1];
    const float* roi    = (const float*)d_in[2];
    const float* W1     = (const float*)d_in[3];
    const float* b1     = (const float*)d_in[4];
    const float* Wc     = (const float*)d_in[5];
    const float* bc     = (const float*)d_in[6];
    const float* Wr     = (const float*)d_in[7];
    const float* br     = (const float*)d_in[8];
    float* out = (float*)d_out;

    char* ws = (char*)d_ws;
    // byte offsets (all 64-aligned)
    const size_t O_RANK   = 0;         // int[6000]            24000
    const size_t O_ORDER  = 24064;     // int[6000]            24000
    const size_t O_SBOX   = 48128;     // float4[6000]         96000
    const size_t O_BITMAP = 144128;    // u64[12000]           96000
    const size_t O_MASK   = 240128;    // u64[6000*94]         4512000
    const size_t O_KEEPF  = 4752128;   // float[6000]          24000
    const size_t O_FLAT   = 4776128;   // u16[6000*256]        3072000
    const size_t O_W1T    = 7848128;   // u16[1024*256]        524288
    const size_t O_W2T    = 8372416;   // u16[32*1024]         65536
    const size_t O_H      = 8437952;   // u16[6000*1024]       12288000
    const size_t O_SCORES = 20725952;  // float[6000*32]       768000

    int*    rank   = (int*)(ws + O_RANK);
    int*    order  = (int*)(ws + O_ORDER);
    float4* sboxes = (float4*)(ws + O_SBOX);
    u64*    bitmap = (u64*)(ws + O_BITMAP);
    u64*    mask   = (u64*)(ws + O_MASK);
    float*  keepF  = (float*)(ws + O_KEEPF);
    u16*    flat   = (u16*)(ws + O_FLAT);
    u16*    w1t    = (u16*)(ws + O_W1T);
    u16*    w2t    = (u16*)(ws + O_W2T);
    u16*    h      = (u16*)(ws + O_H);
    float*  sc2    = (float*)(ws + O_SCORES);

    hipMemsetAsync(ws + O_RANK, 0, 24000, stream);
    hipMemsetAsync(ws + O_BITMAP, 0, 96000, stream);

    // big BW kernel first
    pool_kernel<<<1500, 256, 0, stream>>>(roi, flat);
    prep_w1t<<<1024, 256, 0, stream>>>(W1, w1t);
    prep_w2t<<<128, 256, 0, stream>>>(Wc, Wr, w2t);

    rank_kernel<<<dim3(24, 24), 256, 0, stream>>>(scores, rank);
    scatter_kernel<<<24, 256, 0, stream>>>(boxes, rank, order, sboxes);
    mask_kernel<<<dim3(CB94, CB94), 64, 0, stream>>>(sboxes, mask, bitmap);

    gemm1_kernel<<<dim3(8, 47), 256, 0, stream>>>(flat, w1t, b1, h);

    scan_kernel<<<1, 256, 0, stream>>>(mask, bitmap, order, keepF, out);

    gemm2_kernel<<<CB94, 256, 0, stream>>>(h, w2t, sc2);
    epilogue_kernel<<<24, 256, 0, stream>>>(sc2, keepF, bc, br, out);
}